// Round 6
// baseline (557.330 us; speedup 1.0000x reference)
//
#include <hip/hip_runtime.h>
#include <math.h>

#define NPTS 4096
#define KNN 16
#define LN_EPS 1e-5f

// KNN tuning
#define BOOT 128    // exact serial bootstrap length (all 4 waves, redundant, identical)
#define CAP0 32     // wave-0 replayable pairs-buffer slots
#define TRIG 24     // wave-0 replay trigger (max group growth 8 => slots stay < CAP0)
#define CAP1 72     // waves 1-3 j-only buffer slots (+1 spare slot allocated)
#define C1S  928    // wave-0 exact region [BOOT, C1S); chunks of 1056 follow
#define CHSZ 1056   // chunk size for waves 1-3
#define SEG  352    // gating segment = CHSZ/3 (44 groups of 8)

// ---------------------------------------------------------------------------
// FROZEN ORACLE (r17 PASS, r19 falsified stable-top16): np's neighbor sets
// are reproduced by the r17 SERIAL algorithm exactly:
//   d2: sq=(x2+y2)+z2 seq; dot=fma(z,z',fma(y,y',x*x')); d2=(sqn+sqm)-(2*dot)
//   selection: ascending-j scan, admission `d2 < ld[15]` (strict, d2-only),
//   16-deep displaced-carry insert chain comparing d2 ONLY.
// Transients matter (equal-d2 scramble) => any filter threshold must dominate
// ld15(j-) at every tested j. DO NOT modify admission/insert semantics.
//
// KNN r24 (UNCHANGED — works): generation-gated thresholds.
// FUSE r26: r25 global-weight structure + REGISTER PRELOAD of weight columns
// (r25 regression diagnosed: launch_bounds(256,6) -> VGPR=32 -> compiler
// issued each weight load right before use -> latency-bound at 53% VALUBusy).
// w1 preloaded at entry (latency hidden under pw2 staging + pos-MLP + barrier
// + section-1 gathers); sched_barrier(0) then w2 preload (hidden under LN
// shuffle chains). launch_bounds(256,4) = 128 VGPR cap, 16 waves/CU.
// ---------------------------------------------------------------------------

__global__ __launch_bounds__(256) void proj3_kernel(
    const float* __restrict__ x, const float* __restrict__ Wq,
    const float* __restrict__ Wk, const float* __restrict__ Wv,
    float* __restrict__ qf, float* __restrict__ kf, float* __restrict__ vf) {
  int g = blockIdx.x * 256 + threadIdx.x;
  int r = g >> 6, c = g & 63;
  float sq = 0.f, sk = 0.f, sv = 0.f;
  for (int i = 0; i < 64; ++i) {
    float xv = x[r*64 + i];
    sq += xv * Wq[i*64 + c];
    sk += xv * Wk[i*64 + c];
    sv += xv * Wv[i*64 + c];
  }
  qf[g] = sq; kf[g] = sk; vf[g] = sv;
}

// Pre-transpose a_w1/a_w2 [i][c] -> [c][i] in workspace (values untouched).
__global__ __launch_bounds__(256) void wtrans_kernel(
    const float* __restrict__ a_w1, const float* __restrict__ a_w2,
    float* __restrict__ w1t, float* __restrict__ w2t) {
  int e = blockIdx.x * 256 + threadIdx.x;   // 16 blocks x 256 = 4096
  int i = e >> 6, c = e & 63;
  w1t[c*64 + i] = a_w1[e];
  w2t[c*64 + i] = a_w2[e];
}

// Verbatim r17 displaced-carry insert chain (frozen oracle — do not touch).
#define INSERT_CHAIN(DD, JJ)                                          \
  do {                                                                \
    float dd = (DD); int jj = (JJ);                                   \
    _Pragma("unroll")                                                 \
    for (int v = 0; v < 16; ++v) {                                    \
      bool sw = dd < ld[v];                                           \
      float nd = sw ? dd : ld[v]; float td = sw ? ld[v] : dd;         \
      int   nj = sw ? jj : lj[v]; int   tj = sw ? lj[v] : jj;         \
      ld[v] = nd; lj[v] = nj; dd = td; jj = tj;                       \
    }                                                                 \
  } while (0)

// Wave-0 replay: pop buffered pairs in ascending-j (push) order with the
// EXACT evolving admission, then tighten + publish the threshold value.
#define REPLAY0()                                                     \
  do {                                                                \
    for (int i = 0; ; ++i) {                                          \
      unsigned long long alive = __ballot(i < cnt);                   \
      if (!alive) break;                                              \
      if (i < cnt) {                                                  \
        float dd0 = s_buf0[i*128 + bo];                               \
        int   jj0 = __float_as_int(s_buf0[i*128 + bo + 1]);           \
        if (dd0 < ld[15]) INSERT_CHAIN(dd0, jj0);                     \
      }                                                               \
    }                                                                 \
    cnt = 0; thr = ld[15]; s_thr[tid] = thr;                          \
  } while (0)

// One 8-candidate group: verbatim V1 d2 arithmetic.
#define GROUP_D2(SBASE)                                               \
  float4 p[8];                                                        \
  _Pragma("unroll")                                                   \
  for (int u = 0; u < 8; ++u) p[u] = s_p[(SBASE) + u];                \
  float d2v[8];                                                       \
  _Pragma("unroll")                                                   \
  for (int u = 0; u < 8; ++u) {                                       \
    float acc = __fmul_rn(qx, p[u].x);                                \
    acc = __fmaf_rn(qy, p[u].y, acc);                                 \
    acc = __fmaf_rn(qz, p[u].z, acc);                                 \
    d2v[u] = __fsub_rn(__fadd_rn(sqn, p[u].w), __fmul_rn(2.0f, acc)); \
  }

// Branchless store-offset tree: flags independent, offsets via 3-level adds.
#define TREE_OFFS(THRV)                                               \
  int f0 = (d2v[0] < (THRV)) ? 1 : 0, f1 = (d2v[1] < (THRV)) ? 1 : 0, \
      f2 = (d2v[2] < (THRV)) ? 1 : 0, f3 = (d2v[3] < (THRV)) ? 1 : 0, \
      f4 = (d2v[4] < (THRV)) ? 1 : 0, f5 = (d2v[5] < (THRV)) ? 1 : 0, \
      f6 = (d2v[6] < (THRV)) ? 1 : 0, f7 = (d2v[7] < (THRV)) ? 1 : 0; \
  int s01 = f0+f1, s23 = f2+f3, s45 = f4+f5, s67 = f6+f7;             \
  int s03 = s01+s23, s47 = s45+s67;                                   \
  int o[8];                                                           \
  o[0] = cnt;        o[1] = cnt + f0;   o[2] = cnt + s01;             \
  o[3] = cnt + s01 + f2;                o[4] = cnt + s03;             \
  o[5] = o[4] + f4;  o[6] = o[4] + s45; o[7] = o[6] + f6;

__global__ __launch_bounds__(256) void knn_gated4_kernel(
    const float* __restrict__ pos, int* __restrict__ idx_out) {
  __shared__ __align__(16) float4 s_p[NPTS];           // 64 KB (x,y,z,sq)
  __shared__ __align__(16) float  s_buf0[CAP0*128];    // 16 KB wave-0 (d2,j) pairs
  __shared__ int   s_j1[3][(CAP1+1)*64];               // 54.75 KB j-only buffers
  __shared__ float s_thr[64];                          // published exact ld15(P)
  __shared__ int   s_cnt1[3][64];
  __shared__ int   s_gen;                              // publish generation
  __shared__ int   s_ovf;

  int t = threadIdx.x;
  int tid = t & 63, w = t >> 6, b = blockIdx.y;
  const float* pb = pos + b*NPTS*3;
  for (int j = t; j < NPTS; j += 256) {
    float px = pb[j*3+0], py = pb[j*3+1], pz = pb[j*3+2];
    float sq = __fadd_rn(__fadd_rn(__fmul_rn(px,px), __fmul_rn(py,py)),
                         __fmul_rn(pz,pz));
    s_p[j] = make_float4(px, py, pz, sq);
  }
  if (t < 64) s_thr[t] = INFINITY;
  if (t == 0) { s_ovf = 0; s_gen = 0; }
  __syncthreads();

  int n = blockIdx.x * 64 + tid;
  float4 qp = s_p[n];
  float qx = qp.x, qy = qp.y, qz = qp.z, sqn = qp.w;
  float ld[16]; int lj[16];
#pragma unroll
  for (int u = 0; u < 16; ++u) { ld[u] = INFINITY; lj[u] = 0x7fffffff; }

  // --- exact bootstrap [0, BOOT): all 4 waves run identically (deterministic,
  //     per-lane chain => same ld/lj/thr everywhere) ---
  for (int s = 0; s < BOOT; s += 8) {
    GROUP_D2(s)
#pragma unroll
    for (int u = 0; u < 8; ++u) {
      float d2 = d2v[u];
      if (d2 < ld[15]) INSERT_CHAIN(d2, s + u);
    }
  }
  float thr = ld[15];
  int bo = tid << 1;
  int cnt = 0;

  if (w == 0) {
    // --- wave 0: exact filter+replay over [BOOT, C1S), gated publishes ---
    for (int s = BOOT; s < C1S; s += 8) {
      GROUP_D2(s)
      TREE_OFFS(thr)
#pragma unroll
      for (int u = 0; u < 8; ++u) {
        s_buf0[o[u]*128 + bo]     = d2v[u];
        s_buf0[o[u]*128 + bo + 1] = __int_as_float(s + u);
      }
      cnt += s03 + s47;
      int done = s + 8;
      bool pub = ((done & 127) == 0) && done >= 256 && done <= 896;
      if (pub || __ballot(cnt >= TRIG) != 0ULL) {
        REPLAY0();                       // state exact through `done`
        if (pub) {
          __threadfence_block();         // drain s_thr writes
          s_gen = (done >> 7) - 1;       // 256->1 ... 896->6
        }
      }
    }
    REPLAY0();          // state now == exact serial through j < C1S
    __syncthreads();    // waves 1-3 finished buffering

    int ovf = s_ovf;
    for (int ch = 0; ch < 3; ++ch) {
      int cs = C1S + ch*CHSZ;
      if (ovf & (1 << ch)) {
        // exact serial fallback over this chunk (correctness guarantee)
        int ce = cs + CHSZ;
        for (int s = cs; s < ce; s += 8) {
          GROUP_D2(s)
          TREE_OFFS(thr)
#pragma unroll
          for (int u = 0; u < 8; ++u) {
            s_buf0[o[u]*128 + bo]     = d2v[u];
            s_buf0[o[u]*128 + bo + 1] = __int_as_float(s + u);
          }
          cnt += s03 + s47;
          if (__ballot(cnt >= TRIG) != 0ULL) REPLAY0();
        }
        REPLAY0();
      } else {
        // merge-replay chunk buffer (ascending j, exact admission), pipelined
        const int* jb = &s_j1[ch][0];
        int cc = s_cnt1[ch][tid];
        int jn = (0 < cc) ? jb[tid] : 0;
        float4 pn = s_p[jn];
        for (int i = 0; ; ++i) {
          unsigned long long alive = __ballot(i < cc);
          if (!alive) break;
          int jj0 = jn; float4 pj = pn;
          int ix = i + 1;
          jn = (ix < cc) ? jb[ix*64 + tid] : 0;
          pn = s_p[jn];
          if (i < cc) {
            // bit-identical d2 recompute (same inputs, same fp ops as filter)
            float acc = __fmul_rn(qx, pj.x);
            acc = __fmaf_rn(qy, pj.y, acc);
            acc = __fmaf_rn(qz, pj.z, acc);
            float dd0 = __fsub_rn(__fadd_rn(sqn, pj.w), __fmul_rn(2.0f, acc));
            if (dd0 < ld[15]) INSERT_CHAIN(dd0, jj0);
          }
        }
      }
    }
    int* outp = idx_out + (b*NPTS + n)*KNN;
#pragma unroll
    for (int u = 0; u < 16; ++u) outp[u] = b*NPTS + lj[u];   // GLOBAL row index
  } else {
    // --- waves 1-3: gen-gated superset filter over their chunk, j-only ---
    int cs = C1S + (w-1)*CHSZ;
    int* jb = &s_j1[w-1][0];
    float thrW = thr;
#pragma unroll
    for (int seg = 0; seg < 3; ++seg) {
      int need = 2*seg + 2;                       // gens 2,4,6 -> P=384,640,896
      while (*((volatile int*)&s_gen) < need) __builtin_amdgcn_s_sleep(2);
      thrW = fminf(thrW, *((volatile float*)&s_thr[tid]));
      int ss = cs + seg*SEG, se = ss + SEG;
      for (int s = ss; s < se; s += 8) {
        GROUP_D2(s)
        TREE_OFFS(thrW)
#pragma unroll
        for (int u = 0; u < 8; ++u) {
          int oc = (o[u] <= CAP1) ? o[u] : CAP1;   // spare slot absorbs junk
          jb[oc*64 + tid] = s + u;
        }
        cnt += s03 + s47;
      }
    }
    s_cnt1[w-1][tid] = (cnt <= CAP1) ? cnt : CAP1;
    if (cnt > CAP1) atomicOr(&s_ovf, 1 << (w-1));
    __syncthreads();
  }
}

// ---------------------------------------------------------------------------
// Fused layer r26: r25 structure + register-preloaded weight columns.
// w1 column loaded into 16 float4 regs at ENTRY (latency hidden under pw2
// staging, pos-MLP, barrier, section-1 gathers). sched_barrier(0) after
// matmul1, then w2 column loaded (hidden under LN shuffle chains; also keeps
// peak VGPR = one weight array + working set, fitting the 128-reg cap).
// Matmul inner loops are pure readlane+FMA, zero memory ops. FMA order
// ascending i with identical values => bit-identical output.
// 12 KB LDS; launch_bounds(256,4) => 4 blocks/CU, 16 waves/CU.
// ---------------------------------------------------------------------------
__device__ __forceinline__ float wsum64(float v) {
  v += __shfl_xor(v, 1);
  v += __shfl_xor(v, 2);
  v += __shfl_xor(v, 4);
  v += __shfl_xor(v, 8);
  v += __shfl_xor(v, 16);
  v += __shfl_xor(v, 32);
  return v;
}

__device__ __forceinline__ float bcast(float v, int lane) {
  return __int_as_float(__builtin_amdgcn_readlane(__float_as_int(v), lane));
}

__global__ __launch_bounds__(256, 4) void fuse_kernel(
    const float* __restrict__ pos, const int* __restrict__ idx,
    const float* __restrict__ qf, const float* __restrict__ kf,
    const float* __restrict__ vf,
    const float* __restrict__ p_w1, const float* __restrict__ p_b1,
    const float* __restrict__ p_g, const float* __restrict__ p_be,
    const float* __restrict__ p_w2, const float* __restrict__ p_b2,
    const float* __restrict__ w1t, const float* __restrict__ a_b1,
    const float* __restrict__ a_g, const float* __restrict__ a_be,
    const float* __restrict__ w2t, const float* __restrict__ a_b2,
    float* __restrict__ out) {
  __shared__ int   s_j[16];
  __shared__ float s_h[16][12];
  __shared__ __align__(16) float s_ve[16][64];
  __shared__ __align__(16) float s_t2[16][64];
  __shared__ float s_pw2[768];                    // p_w2 [h][c]

  int tid = threadIdx.x;
  int p = blockIdx.x;
  int c = tid & 63, kq = tid >> 6;

  // --- preload w1 column into registers (issued first; consumed in matmul1) ---
  const float* w1c = w1t + c*64;
  float4 wv1[16];
#pragma unroll
  for (int ii = 0; ii < 16; ++ii) wv1[ii] = *(const float4*)(w1c + 4*ii);

  for (int e = tid; e < 768; e += 256) s_pw2[e] = p_w2[e];

  if (tid < 16) {
    int j = idx[p*KNN + tid];
    s_j[tid] = j;
    float rx = pos[p*3+0] - pos[j*3+0];
    float ry = pos[p*3+1] - pos[j*3+1];
    float rz = pos[p*3+2] - pos[j*3+2];
    float hv[12];
    float mean = 0.f;
#pragma unroll
    for (int h = 0; h < 12; ++h) {
      float v = rx*p_w1[h] + ry*p_w1[12+h] + rz*p_w1[24+h] + p_b1[h];
      hv[h] = v; mean += v;
    }
    mean *= (1.0f/12.0f);
    float var = 0.f;
#pragma unroll
    for (int h = 0; h < 12; ++h) { float d = hv[h] - mean; var += d*d; }
    var *= (1.0f/12.0f);
    float rs = rsqrtf(var + LN_EPS);
#pragma unroll
    for (int h = 0; h < 12; ++h) {
      float a = (hv[h] - mean)*rs*p_g[h] + p_be[h];
      s_h[tid][h] = fmaxf(a, 0.f);
    }
  }
  __syncthreads();

  // --- section 1: pos-enc + win (REGISTERS) + ve (LDS, needed by softmax) ---
  float win0, win1, win2, win3;   // win[k][c], k = kq, 4+kq, 8+kq, 12+kq
  {
    float qv = qf[p*64 + c];
    float pb2 = p_b2[c];
    float pe0 = pb2, pe1 = pb2, pe2 = pb2, pe3 = pb2;
#pragma unroll
    for (int h = 0; h < 12; ++h) {
      float wv = s_pw2[h*64 + c];
      pe0 = __fmaf_rn(s_h[kq][h],    wv, pe0);
      pe1 = __fmaf_rn(s_h[4+kq][h],  wv, pe1);
      pe2 = __fmaf_rn(s_h[8+kq][h],  wv, pe2);
      pe3 = __fmaf_rn(s_h[12+kq][h], wv, pe3);
    }
    int j0 = s_j[kq], j1 = s_j[4+kq], j2 = s_j[8+kq], j3 = s_j[12+kq];
    win0 = qv - kf[j0*64 + c] + pe0;  s_ve[kq][c]    = vf[j0*64 + c] + pe0;
    win1 = qv - kf[j1*64 + c] + pe1;  s_ve[4+kq][c]  = vf[j1*64 + c] + pe1;
    win2 = qv - kf[j2*64 + c] + pe2;  s_ve[8+kq][c]  = vf[j2*64 + c] + pe2;
    win3 = qv - kf[j3*64 + c] + pe3;  s_ve[12+kq][c] = vf[j3*64 + c] + pe3;
  }

  // --- matmul1: ai = win @ a_w1 + b1 (readlane broadcast, weights in regs) ---
  float ab1 = a_b1[c];
  float a0 = ab1, a1 = ab1, a2 = ab1, a3 = ab1;
#pragma unroll
  for (int ii = 0; ii < 16; ++ii) {
    float4 wa = wv1[ii];
#pragma unroll
    for (int q = 0; q < 4; ++q) {
      int i = 4*ii + q;
      float wv = (q == 0) ? wa.x : (q == 1) ? wa.y : (q == 2) ? wa.z : wa.w;
      float b0 = bcast(win0, i), b1 = bcast(win1, i);
      float b2 = bcast(win2, i), b3 = bcast(win3, i);
      a0 = __fmaf_rn(b0, wv, a0);
      a1 = __fmaf_rn(b1, wv, a1);
      a2 = __fmaf_rn(b2, wv, a2);
      a3 = __fmaf_rn(b3, wv, a3);
    }
  }

  // fence: keep w2 loads below matmul1 (caps peak VGPR at one weight array)
  __builtin_amdgcn_sched_barrier(0);

  // --- preload w2 column (latency hidden under the LN shuffle chains) ---
  const float* w2c = w2t + c*64;
  float4 wv2[16];
#pragma unroll
  for (int ii = 0; ii < 16; ++ii) wv2[ii] = *(const float4*)(w2c + 4*ii);

  // --- LN + ReLU in registers (same butterfly order as r22) ---
  float ag = a_g[c], abe = a_be[c];
  float r0, r1, r2, r3;
  {
    float m = wsum64(a0) * (1.0f/64.0f); float d = a0 - m;
    float var = wsum64(d*d) * (1.0f/64.0f);
    r0 = fmaxf(d*rsqrtf(var + LN_EPS)*ag + abe, 0.f);
  }
  {
    float m = wsum64(a1) * (1.0f/64.0f); float d = a1 - m;
    float var = wsum64(d*d) * (1.0f/64.0f);
    r1 = fmaxf(d*rsqrtf(var + LN_EPS)*ag + abe, 0.f);
  }
  {
    float m = wsum64(a2) * (1.0f/64.0f); float d = a2 - m;
    float var = wsum64(d*d) * (1.0f/64.0f);
    r2 = fmaxf(d*rsqrtf(var + LN_EPS)*ag + abe, 0.f);
  }
  {
    float m = wsum64(a3) * (1.0f/64.0f); float d = a3 - m;
    float var = wsum64(d*d) * (1.0f/64.0f);
    r3 = fmaxf(d*rsqrtf(var + LN_EPS)*ag + abe, 0.f);
  }

  // --- matmul2: t2 = act @ a_w2 + b2 ---
  float ab2 = a_b2[c];
  float t0 = ab2, t1 = ab2, t2 = ab2, t3 = ab2;
#pragma unroll
  for (int ii = 0; ii < 16; ++ii) {
    float4 wa = wv2[ii];
#pragma unroll
    for (int q = 0; q < 4; ++q) {
      int i = 4*ii + q;
      float wv = (q == 0) ? wa.x : (q == 1) ? wa.y : (q == 2) ? wa.z : wa.w;
      float b0 = bcast(r0, i), b1 = bcast(r1, i);
      float b2 = bcast(r2, i), b3 = bcast(r3, i);
      t0 = __fmaf_rn(b0, wv, t0);
      t1 = __fmaf_rn(b1, wv, t1);
      t2 = __fmaf_rn(b2, wv, t2);
      t3 = __fmaf_rn(b3, wv, t3);
    }
  }
  s_t2[kq][c]    = t0;
  s_t2[4+kq][c]  = t1;
  s_t2[8+kq][c]  = t2;
  s_t2[12+kq][c] = t3;
  __syncthreads();

  if (tid < 64) {
    float mx = -INFINITY;
    for (int k = 0; k < 16; ++k) mx = fmaxf(mx, s_t2[k][tid]);
    float se = 0.f, po = 0.f;
    for (int k = 0; k < 16; ++k) {
      float e = expf(s_t2[k][tid] - mx);
      se += e; po += e * s_ve[k][tid];
    }
    out[p*64 + tid] = po / se;
  }
}

// ---------------------------------------------------------------------------
extern "C" void kernel_launch(void* const* d_in, const int* in_sizes, int n_in,
                              void* d_out, int out_size, void* d_ws, size_t ws_size,
                              hipStream_t stream) {
  const float* x    = (const float*)d_in[0];
  const float* pos  = (const float*)d_in[1];
  const float* Wq   = (const float*)d_in[2];
  const float* Wk   = (const float*)d_in[3];
  const float* Wv   = (const float*)d_in[4];
  const float* p_w1 = (const float*)d_in[5];
  const float* p_b1 = (const float*)d_in[6];
  const float* p_g  = (const float*)d_in[7];
  const float* p_be = (const float*)d_in[8];
  const float* p_w2 = (const float*)d_in[9];
  const float* p_b2 = (const float*)d_in[10];
  const float* a_w1 = (const float*)d_in[11];
  const float* a_b1 = (const float*)d_in[12];
  const float* a_g  = (const float*)d_in[13];
  const float* a_be = (const float*)d_in[14];
  const float* a_w2 = (const float*)d_in[15];
  const float* a_b2 = (const float*)d_in[16];

  float* ws   = (float*)d_ws;
  float* qf   = ws;                    // 1048576 floats
  float* kf   = qf + 1048576;          // 1048576
  float* vf   = kf + 1048576;          // 1048576
  int*   idx  = (int*)(vf + 1048576);  // 262144 ints
  float* w1t  = (float*)(idx + 262144);// 4096 floats
  float* w2t  = w1t + 4096;            // 4096 floats
  float* outp = (float*)d_out;

  hipLaunchKernelGGL(wtrans_kernel, dim3(16), dim3(256), 0, stream,
                     a_w1, a_w2, w1t, w2t);
  hipLaunchKernelGGL(proj3_kernel, dim3(4096), dim3(256), 0, stream,
                     x, Wq, Wk, Wv, qf, kf, vf);
  hipLaunchKernelGGL(knn_gated4_kernel, dim3(64, 4), dim3(256), 0, stream,
                     pos, idx);
  hipLaunchKernelGGL(fuse_kernel, dim3(16384), dim3(256), 0, stream,
                     pos, idx, qf, kf, vf,
                     p_w1, p_b1, p_g, p_be, p_w2, p_b2,
                     w1t, a_b1, a_g, a_be, w2t, a_b2, outp);
}

// Round 7
// 460.351 us; speedup vs baseline: 1.2107x; 1.2107x over previous
//
#include <hip/hip_runtime.h>
#include <math.h>

#define NPTS 4096
#define KNN 16
#define LN_EPS 1e-5f

// KNN tuning
#define BOOT 128    // exact serial bootstrap length (all 4 waves, redundant, identical)
#define CAP0 32     // wave-0 replayable pairs-buffer slots
#define TRIG 24     // wave-0 replay trigger (max group growth 8 => slots stay < CAP0)
#define CAP1 72     // waves 1-3 j-only buffer slots (+1 spare slot allocated)
#define C1S  928    // wave-0 exact region [BOOT, C1S); chunks of 1056 follow
#define CHSZ 1056   // chunk size for waves 1-3
#define SEG  352    // gating segment = CHSZ/3 (44 groups of 8)

// ---------------------------------------------------------------------------
// FROZEN ORACLE (r17 PASS, r19 falsified stable-top16): np's neighbor sets
// are reproduced by the r17 SERIAL algorithm exactly:
//   d2: sq=(x2+y2)+z2 seq; dot=fma(z,z',fma(y,y',x*x')); d2=(sqn+sqm)-(2*dot)
//   selection: ascending-j scan, admission `d2 < ld[15]` (strict, d2-only),
//   16-deep displaced-carry insert chain comparing d2 ONLY.
// Transients matter (equal-d2 scramble) => any filter threshold must dominate
// ld15(j-) at every tested j. DO NOT modify admission/insert semantics.
//
// KNN r27: r24 generation-gated structure + 2x ping-pong software pipeline of
// the pure s_p group loads (hides ~120cy LDS latency at 1 wave/SIMD). Pure
// read reordering — admission/chain dynamics byte-identical.
// FUSE r27: revert to r24 readlane structure (measured best, 214us) with the
// conflict FIXED: weights staged in natural [i][c] layout, read as per-i
// scalar b32 (64 consecutive floats per i = conflict-free broadcast pattern).
// r25/r26 lesson: global-weight variants trade 120cy LDS latency for
// 200-900cy global latency — stall-bound regardless of scheduling hints.
// ---------------------------------------------------------------------------

__global__ __launch_bounds__(256) void proj3_kernel(
    const float* __restrict__ x, const float* __restrict__ Wq,
    const float* __restrict__ Wk, const float* __restrict__ Wv,
    float* __restrict__ qf, float* __restrict__ kf, float* __restrict__ vf) {
  int g = blockIdx.x * 256 + threadIdx.x;
  int r = g >> 6, c = g & 63;
  float sq = 0.f, sk = 0.f, sv = 0.f;
  for (int i = 0; i < 64; ++i) {
    float xv = x[r*64 + i];
    sq += xv * Wq[i*64 + c];
    sk += xv * Wk[i*64 + c];
    sv += xv * Wv[i*64 + c];
  }
  qf[g] = sq; kf[g] = sk; vf[g] = sv;
}

// Verbatim r17 displaced-carry insert chain (frozen oracle — do not touch).
#define INSERT_CHAIN(DD, JJ)                                          \
  do {                                                                \
    float dd = (DD); int jj = (JJ);                                   \
    _Pragma("unroll")                                                 \
    for (int v = 0; v < 16; ++v) {                                    \
      bool sw = dd < ld[v];                                           \
      float nd = sw ? dd : ld[v]; float td = sw ? ld[v] : dd;         \
      int   nj = sw ? jj : lj[v]; int   tj = sw ? lj[v] : jj;         \
      ld[v] = nd; lj[v] = nj; dd = td; jj = tj;                       \
    }                                                                 \
  } while (0)

// Wave-0 replay: pop buffered pairs in ascending-j (push) order with the
// EXACT evolving admission, then tighten + publish the threshold value.
#define REPLAY0()                                                     \
  do {                                                                \
    for (int i = 0; ; ++i) {                                          \
      unsigned long long alive = __ballot(i < cnt);                   \
      if (!alive) break;                                              \
      if (i < cnt) {                                                  \
        float dd0 = s_buf0[i*128 + bo];                               \
        int   jj0 = __float_as_int(s_buf0[i*128 + bo + 1]);           \
        if (dd0 < ld[15]) INSERT_CHAIN(dd0, jj0);                     \
      }                                                               \
    }                                                                 \
    cnt = 0; thr = ld[15]; s_thr[tid] = thr;                          \
  } while (0)

// Pipelined load/compute pieces (verbatim V1 d2 arithmetic).
#define LOADP(P, SBASE)                                               \
  _Pragma("unroll")                                                   \
  for (int u = 0; u < 8; ++u) P[u] = s_p[(SBASE) + u];

#define D2V(P)                                                        \
  float d2v[8];                                                       \
  _Pragma("unroll")                                                   \
  for (int u = 0; u < 8; ++u) {                                       \
    float acc = __fmul_rn(qx, P[u].x);                                \
    acc = __fmaf_rn(qy, P[u].y, acc);                                 \
    acc = __fmaf_rn(qz, P[u].z, acc);                                 \
    d2v[u] = __fsub_rn(__fadd_rn(sqn, P[u].w), __fmul_rn(2.0f, acc)); \
  }

// Combined (non-pipelined) group for the rare fallback path.
#define GROUP_D2(SBASE) float4 p[8]; LOADP(p, SBASE) D2V(p)

// Branchless store-offset tree: flags independent, offsets via 3-level adds.
#define TREE_OFFS(THRV)                                               \
  int f0 = (d2v[0] < (THRV)) ? 1 : 0, f1 = (d2v[1] < (THRV)) ? 1 : 0, \
      f2 = (d2v[2] < (THRV)) ? 1 : 0, f3 = (d2v[3] < (THRV)) ? 1 : 0, \
      f4 = (d2v[4] < (THRV)) ? 1 : 0, f5 = (d2v[5] < (THRV)) ? 1 : 0, \
      f6 = (d2v[6] < (THRV)) ? 1 : 0, f7 = (d2v[7] < (THRV)) ? 1 : 0; \
  int s01 = f0+f1, s23 = f2+f3, s45 = f4+f5, s67 = f6+f7;             \
  int s03 = s01+s23, s47 = s45+s67;                                   \
  int o[8];                                                           \
  o[0] = cnt;        o[1] = cnt + f0;   o[2] = cnt + s01;             \
  o[3] = cnt + s01 + f2;                o[4] = cnt + s03;             \
  o[5] = o[4] + f4;  o[6] = o[4] + s45; o[7] = o[6] + f6;

// Per-group processing bodies (each self-braced: TREE_OFFS/D2V locals scoped).
#define PROC_BOOT(P, S) {                                             \
    D2V(P)                                                            \
    _Pragma("unroll")                                                 \
    for (int u = 0; u < 8; ++u) {                                     \
      float d2 = d2v[u];                                              \
      if (d2 < ld[15]) INSERT_CHAIN(d2, (S) + u);                     \
    }                                                                 \
  }

#define PROC_W0(P, S) {                                               \
    D2V(P)                                                            \
    TREE_OFFS(thr)                                                    \
    _Pragma("unroll")                                                 \
    for (int u = 0; u < 8; ++u) {                                     \
      s_buf0[o[u]*128 + bo]     = d2v[u];                             \
      s_buf0[o[u]*128 + bo + 1] = __int_as_float((S) + u);            \
    }                                                                 \
    cnt += s03 + s47;                                                 \
    int done = (S) + 8;                                               \
    bool pub = ((done & 127) == 0) && done >= 256 && done <= 896;     \
    if (pub || __ballot(cnt >= TRIG) != 0ULL) {                       \
      REPLAY0();                                                      \
      if (pub) {                                                      \
        __threadfence_block();                                        \
        s_gen = (done >> 7) - 1;                                      \
      }                                                               \
    }                                                                 \
  }

#define PROC_W13(P, S) {                                              \
    D2V(P)                                                            \
    TREE_OFFS(thrW)                                                   \
    _Pragma("unroll")                                                 \
    for (int u = 0; u < 8; ++u) {                                     \
      int oc = (o[u] <= CAP1) ? o[u] : CAP1;                          \
      jb[oc*64 + tid] = (S) + u;                                      \
    }                                                                 \
    cnt += s03 + s47;                                                 \
  }

__global__ __launch_bounds__(256) void knn_gated4_kernel(
    const float* __restrict__ pos, int* __restrict__ idx_out) {
  __shared__ __align__(16) float4 s_p[NPTS];           // 64 KB (x,y,z,sq)
  __shared__ __align__(16) float  s_buf0[CAP0*128];    // 16 KB wave-0 (d2,j) pairs
  __shared__ int   s_j1[3][(CAP1+1)*64];               // 54.75 KB j-only buffers
  __shared__ float s_thr[64];                          // published exact ld15(P)
  __shared__ int   s_cnt1[3][64];
  __shared__ int   s_gen;                              // publish generation
  __shared__ int   s_ovf;

  int t = threadIdx.x;
  int tid = t & 63, w = t >> 6, b = blockIdx.y;
  const float* pb = pos + b*NPTS*3;
  for (int j = t; j < NPTS; j += 256) {
    float px = pb[j*3+0], py = pb[j*3+1], pz = pb[j*3+2];
    float sq = __fadd_rn(__fadd_rn(__fmul_rn(px,px), __fmul_rn(py,py)),
                         __fmul_rn(pz,pz));
    s_p[j] = make_float4(px, py, pz, sq);
  }
  if (t < 64) s_thr[t] = INFINITY;
  if (t == 0) { s_ovf = 0; s_gen = 0; }
  __syncthreads();

  int n = blockIdx.x * 64 + tid;
  float4 qp = s_p[n];
  float qx = qp.x, qy = qp.y, qz = qp.z, sqn = qp.w;
  float ld[16]; int lj[16];
#pragma unroll
  for (int u = 0; u < 16; ++u) { ld[u] = INFINITY; lj[u] = 0x7fffffff; }

  float4 pA[8], pB[8];

  // --- exact bootstrap [0, BOOT): all 4 waves run identically, pipelined ---
  LOADP(pA, 0)
  for (int s = 0; s < BOOT; s += 16) {
    LOADP(pB, s + 8)
    PROC_BOOT(pA, s)
    LOADP(pA, s + 16)        // final iter preloads group at BOOT (in-bounds)
    PROC_BOOT(pB, s + 8)
  }
  float thr = ld[15];
  int bo = tid << 1;
  int cnt = 0;

  if (w == 0) {
    // --- wave 0: exact filter+replay over [BOOT, C1S), gated publishes ---
    // pA already holds the group at BOOT from the bootstrap pipeline.
    for (int s = BOOT; s < C1S; s += 16) {
      LOADP(pB, s + 8)
      PROC_W0(pA, s)
      LOADP(pA, s + 16)      // final iter reads s_p[928..935] (in-bounds, unused)
      PROC_W0(pB, s + 8)
    }
    REPLAY0();          // state now == exact serial through j < C1S
    __syncthreads();    // waves 1-3 finished buffering

    int ovf = s_ovf;
    for (int ch = 0; ch < 3; ++ch) {
      int cs = C1S + ch*CHSZ;
      if (ovf & (1 << ch)) {
        // exact serial fallback over this chunk (correctness guarantee)
        int ce = cs + CHSZ;
        for (int s = cs; s < ce; s += 8) {
          GROUP_D2(s)
          TREE_OFFS(thr)
#pragma unroll
          for (int u = 0; u < 8; ++u) {
            s_buf0[o[u]*128 + bo]     = d2v[u];
            s_buf0[o[u]*128 + bo + 1] = __int_as_float(s + u);
          }
          cnt += s03 + s47;
          if (__ballot(cnt >= TRIG) != 0ULL) REPLAY0();
        }
        REPLAY0();
      } else {
        // merge-replay chunk buffer (ascending j, exact admission), pipelined
        const int* jb = &s_j1[ch][0];
        int cc = s_cnt1[ch][tid];
        int jn = (0 < cc) ? jb[tid] : 0;
        float4 pn = s_p[jn];
        for (int i = 0; ; ++i) {
          unsigned long long alive = __ballot(i < cc);
          if (!alive) break;
          int jj0 = jn; float4 pj = pn;
          int ix = i + 1;
          jn = (ix < cc) ? jb[ix*64 + tid] : 0;
          pn = s_p[jn];
          if (i < cc) {
            // bit-identical d2 recompute (same inputs, same fp ops as filter)
            float acc = __fmul_rn(qx, pj.x);
            acc = __fmaf_rn(qy, pj.y, acc);
            acc = __fmaf_rn(qz, pj.z, acc);
            float dd0 = __fsub_rn(__fadd_rn(sqn, pj.w), __fmul_rn(2.0f, acc));
            if (dd0 < ld[15]) INSERT_CHAIN(dd0, jj0);
          }
        }
      }
    }
    int* outp = idx_out + (b*NPTS + n)*KNN;
#pragma unroll
    for (int u = 0; u < 16; ++u) outp[u] = b*NPTS + lj[u];   // GLOBAL row index
  } else {
    // --- waves 1-3: gen-gated superset filter over their chunk, j-only ---
    int cs = C1S + (w-1)*CHSZ;
    int* jb = &s_j1[w-1][0];
    float thrW = thr;
#pragma unroll 1
    for (int seg = 0; seg < 3; ++seg) {
      int need = 2*seg + 2;                       // gens 2,4,6 -> P=384,640,896
      while (*((volatile int*)&s_gen) < need) __builtin_amdgcn_s_sleep(2);
      thrW = fminf(thrW, *((volatile float*)&s_thr[tid]));
      int ss = cs + seg*SEG, se = ss + SEG;
      LOADP(pA, ss)
      for (int s = ss; s < se; s += 16) {
        LOADP(pB, s + 8)
        PROC_W13(pA, s)
        int sn = s + 16; if (sn >= se) sn = ss;   // uniform clamp (avoids OOB)
        LOADP(pA, sn)
        PROC_W13(pB, s + 8)
      }
    }
    s_cnt1[w-1][tid] = (cnt <= CAP1) ? cnt : CAP1;
    if (cnt > CAP1) atomicOr(&s_ovf, 1 << (w-1));
    __syncthreads();
  }
}

// ---------------------------------------------------------------------------
// Fused layer r27: r24 readlane structure (measured best) with conflict-free
// LDS weights: natural [i][c] layout, per-i scalar b32 read s_w1[i*64+c]
// (64 consecutive floats across the wave = canonical conflict-free pattern).
// Staging is a plain linear copy. Matmul inner loop: 1 ds_read_b32 +
// 4 readlane + 4 FMA per i. FMA order ascending i with identical values
// => bit-identical to r24 output. 44 KB LDS => 3 blocks/CU.
// ---------------------------------------------------------------------------
__device__ __forceinline__ float wsum64(float v) {
  v += __shfl_xor(v, 1);
  v += __shfl_xor(v, 2);
  v += __shfl_xor(v, 4);
  v += __shfl_xor(v, 8);
  v += __shfl_xor(v, 16);
  v += __shfl_xor(v, 32);
  return v;
}

__device__ __forceinline__ float bcast(float v, int lane) {
  return __int_as_float(__builtin_amdgcn_readlane(__float_as_int(v), lane));
}

__global__ __launch_bounds__(256) void fuse_kernel(
    const float* __restrict__ pos, const int* __restrict__ idx,
    const float* __restrict__ qf, const float* __restrict__ kf,
    const float* __restrict__ vf,
    const float* __restrict__ p_w1, const float* __restrict__ p_b1,
    const float* __restrict__ p_g, const float* __restrict__ p_be,
    const float* __restrict__ p_w2, const float* __restrict__ p_b2,
    const float* __restrict__ a_w1, const float* __restrict__ a_b1,
    const float* __restrict__ a_g, const float* __restrict__ a_be,
    const float* __restrict__ a_w2, const float* __restrict__ a_b2,
    float* __restrict__ out) {
  __shared__ int   s_j[16];
  __shared__ float s_h[16][12];
  __shared__ __align__(16) float s_ve[16][64];
  __shared__ __align__(16) float s_t2[16][64];
  __shared__ float s_pw2[768];                    // p_w2 [h][c]
  __shared__ float s_w1[4096];                    // a_w1 natural [i][c]
  __shared__ float s_w2[4096];                    // a_w2 natural [i][c]

  int tid = threadIdx.x;
  int p = blockIdx.x;
  int c = tid & 63, kq = tid >> 6;

  // linear staging (coalesced global reads, conflict-free LDS writes)
  for (int e = tid; e < 4096; e += 256) { s_w1[e] = a_w1[e]; s_w2[e] = a_w2[e]; }
  for (int e = tid; e < 768; e += 256) s_pw2[e] = p_w2[e];

  if (tid < 16) {
    int j = idx[p*KNN + tid];
    s_j[tid] = j;
    float rx = pos[p*3+0] - pos[j*3+0];
    float ry = pos[p*3+1] - pos[j*3+1];
    float rz = pos[p*3+2] - pos[j*3+2];
    float hv[12];
    float mean = 0.f;
#pragma unroll
    for (int h = 0; h < 12; ++h) {
      float v = rx*p_w1[h] + ry*p_w1[12+h] + rz*p_w1[24+h] + p_b1[h];
      hv[h] = v; mean += v;
    }
    mean *= (1.0f/12.0f);
    float var = 0.f;
#pragma unroll
    for (int h = 0; h < 12; ++h) { float d = hv[h] - mean; var += d*d; }
    var *= (1.0f/12.0f);
    float rs = rsqrtf(var + LN_EPS);
#pragma unroll
    for (int h = 0; h < 12; ++h) {
      float a = (hv[h] - mean)*rs*p_g[h] + p_be[h];
      s_h[tid][h] = fmaxf(a, 0.f);
    }
  }
  __syncthreads();

  // --- section 1: pos-enc + win (REGISTERS) + ve (LDS, needed by softmax) ---
  float win0, win1, win2, win3;   // win[k][c], k = kq, 4+kq, 8+kq, 12+kq
  {
    float qv = qf[p*64 + c];
    float pb2 = p_b2[c];
    float pe0 = pb2, pe1 = pb2, pe2 = pb2, pe3 = pb2;
#pragma unroll
    for (int h = 0; h < 12; ++h) {
      float wv = s_pw2[h*64 + c];
      pe0 = __fmaf_rn(s_h[kq][h],    wv, pe0);
      pe1 = __fmaf_rn(s_h[4+kq][h],  wv, pe1);
      pe2 = __fmaf_rn(s_h[8+kq][h],  wv, pe2);
      pe3 = __fmaf_rn(s_h[12+kq][h], wv, pe3);
    }
    int j0 = s_j[kq], j1 = s_j[4+kq], j2 = s_j[8+kq], j3 = s_j[12+kq];
    win0 = qv - kf[j0*64 + c] + pe0;  s_ve[kq][c]    = vf[j0*64 + c] + pe0;
    win1 = qv - kf[j1*64 + c] + pe1;  s_ve[4+kq][c]  = vf[j1*64 + c] + pe1;
    win2 = qv - kf[j2*64 + c] + pe2;  s_ve[8+kq][c]  = vf[j2*64 + c] + pe2;
    win3 = qv - kf[j3*64 + c] + pe3;  s_ve[12+kq][c] = vf[j3*64 + c] + pe3;
  }

  // --- matmul1: ai = win @ a_w1 + b1 (readlane broadcast, b32 weight read) ---
  float ab1 = a_b1[c];
  float a0 = ab1, a1 = ab1, a2 = ab1, a3 = ab1;
#pragma unroll
  for (int i = 0; i < 64; ++i) {
    float wv = s_w1[i*64 + c];      // conflict-free: 64 consecutive floats
    float b0 = bcast(win0, i), b1 = bcast(win1, i);
    float b2 = bcast(win2, i), b3 = bcast(win3, i);
    a0 = __fmaf_rn(b0, wv, a0);
    a1 = __fmaf_rn(b1, wv, a1);
    a2 = __fmaf_rn(b2, wv, a2);
    a3 = __fmaf_rn(b3, wv, a3);
  }

  // --- LN + ReLU in registers (same butterfly order as r22) ---
  float ag = a_g[c], abe = a_be[c];
  float r0, r1, r2, r3;
  {
    float m = wsum64(a0) * (1.0f/64.0f); float d = a0 - m;
    float var = wsum64(d*d) * (1.0f/64.0f);
    r0 = fmaxf(d*rsqrtf(var + LN_EPS)*ag + abe, 0.f);
  }
  {
    float m = wsum64(a1) * (1.0f/64.0f); float d = a1 - m;
    float var = wsum64(d*d) * (1.0f/64.0f);
    r1 = fmaxf(d*rsqrtf(var + LN_EPS)*ag + abe, 0.f);
  }
  {
    float m = wsum64(a2) * (1.0f/64.0f); float d = a2 - m;
    float var = wsum64(d*d) * (1.0f/64.0f);
    r2 = fmaxf(d*rsqrtf(var + LN_EPS)*ag + abe, 0.f);
  }
  {
    float m = wsum64(a3) * (1.0f/64.0f); float d = a3 - m;
    float var = wsum64(d*d) * (1.0f/64.0f);
    r3 = fmaxf(d*rsqrtf(var + LN_EPS)*ag + abe, 0.f);
  }

  // --- matmul2: t2 = act @ a_w2 + b2 ---
  float ab2 = a_b2[c];
  float t0 = ab2, t1 = ab2, t2 = ab2, t3 = ab2;
#pragma unroll
  for (int i = 0; i < 64; ++i) {
    float wv = s_w2[i*64 + c];
    float b0 = bcast(r0, i), b1 = bcast(r1, i);
    float b2 = bcast(r2, i), b3 = bcast(r3, i);
    t0 = __fmaf_rn(b0, wv, t0);
    t1 = __fmaf_rn(b1, wv, t1);
    t2 = __fmaf_rn(b2, wv, t2);
    t3 = __fmaf_rn(b3, wv, t3);
  }
  s_t2[kq][c]    = t0;
  s_t2[4+kq][c]  = t1;
  s_t2[8+kq][c]  = t2;
  s_t2[12+kq][c] = t3;
  __syncthreads();

  if (tid < 64) {
    float mx = -INFINITY;
    for (int k = 0; k < 16; ++k) mx = fmaxf(mx, s_t2[k][tid]);
    float se = 0.f, po = 0.f;
    for (int k = 0; k < 16; ++k) {
      float e = expf(s_t2[k][tid] - mx);
      se += e; po += e * s_ve[k][tid];
    }
    out[p*64 + tid] = po / se;
  }
}

// ---------------------------------------------------------------------------
extern "C" void kernel_launch(void* const* d_in, const int* in_sizes, int n_in,
                              void* d_out, int out_size, void* d_ws, size_t ws_size,
                              hipStream_t stream) {
  const float* x    = (const float*)d_in[0];
  const float* pos  = (const float*)d_in[1];
  const float* Wq   = (const float*)d_in[2];
  const float* Wk   = (const float*)d_in[3];
  const float* Wv   = (const float*)d_in[4];
  const float* p_w1 = (const float*)d_in[5];
  const float* p_b1 = (const float*)d_in[6];
  const float* p_g  = (const float*)d_in[7];
  const float* p_be = (const float*)d_in[8];
  const float* p_w2 = (const float*)d_in[9];
  const float* p_b2 = (const float*)d_in[10];
  const float* a_w1 = (const float*)d_in[11];
  const float* a_b1 = (const float*)d_in[12];
  const float* a_g  = (const float*)d_in[13];
  const float* a_be = (const float*)d_in[14];
  const float* a_w2 = (const float*)d_in[15];
  const float* a_b2 = (const float*)d_in[16];

  float* ws   = (float*)d_ws;
  float* qf   = ws;                    // 1048576 floats
  float* kf   = qf + 1048576;          // 1048576
  float* vf   = kf + 1048576;          // 1048576
  int*   idx  = (int*)(vf + 1048576);  // 262144 ints
  float* outp = (float*)d_out;

  hipLaunchKernelGGL(proj3_kernel, dim3(4096), dim3(256), 0, stream,
                     x, Wq, Wk, Wv, qf, kf, vf);
  hipLaunchKernelGGL(knn_gated4_kernel, dim3(64, 4), dim3(256), 0, stream,
                     pos, idx);
  hipLaunchKernelGGL(fuse_kernel, dim3(16384), dim3(256), 0, stream,
                     pos, idx, qf, kf, vf,
                     p_w1, p_b1, p_g, p_be, p_w2, p_b2,
                     a_w1, a_b1, a_g, a_be, a_w2, a_b2, outp);
}

// Round 8
// 430.615 us; speedup vs baseline: 1.2943x; 1.0691x over previous
//
#include <hip/hip_runtime.h>
#include <math.h>

#define NPTS 4096
#define KNN 16
#define LN_EPS 1e-5f

// KNN tuning
#define BOOT 128    // exact serial bootstrap length (all 4 waves, redundant, identical)
#define CAP0 32     // wave-0 replayable pairs-buffer slots
#define TRIG 24     // wave-0 replay trigger (max group growth 8 => slots stay < CAP0)
#define CAP1 72     // waves 1-3 j-only buffer slots (+1 spare slot allocated)
#define C1S  928    // wave-0 exact region [BOOT, C1S); chunks of 1056 follow
#define CHSZ 1056   // chunk size for waves 1-3
#define SEG  352    // gating segment = CHSZ/3 (44 groups of 8)

// ---------------------------------------------------------------------------
// FROZEN ORACLE (r17 PASS, r19 falsified stable-top16): np's neighbor sets
// are reproduced by the r17 SERIAL algorithm exactly:
//   d2: sq=(x2+y2)+z2 seq; dot=fma(z,z',fma(y,y',x*x')); d2=(sqn+sqm)-(2*dot)
//   selection: ascending-j scan, admission `d2 < ld[15]` (strict, d2-only),
//   16-deep displaced-carry insert chain comparing d2 ONLY.
// Transients matter (equal-d2 scramble) => any filter threshold must dominate
// ld15(j-) at every tested j. DO NOT modify admission/insert semantics.
//
// KNN r28: r27 gated+pipelined structure + slot prefetch inside REPLAY0
// (the merge loop already had it). Pure read reordering; dynamics identical.
// FUSE r28: r27 structure (measured best: conflicts 0, VALU 77.6%) +
// LDS aliasing: s_j/s_h/s_pw2 (dead after section 1) live inside s_t2's
// storage (written only after matmul2; extra barrier after section 1 makes
// the reuse race-free). LDS = exactly 40960 B => 4 blocks/CU (was 3).
// Weight staging vectorized to float4 (values byte-identical).
// ---------------------------------------------------------------------------

__global__ __launch_bounds__(256) void proj3_kernel(
    const float* __restrict__ x, const float* __restrict__ Wq,
    const float* __restrict__ Wk, const float* __restrict__ Wv,
    float* __restrict__ qf, float* __restrict__ kf, float* __restrict__ vf) {
  int g = blockIdx.x * 256 + threadIdx.x;
  int r = g >> 6, c = g & 63;
  float sq = 0.f, sk = 0.f, sv = 0.f;
  for (int i = 0; i < 64; ++i) {
    float xv = x[r*64 + i];
    sq += xv * Wq[i*64 + c];
    sk += xv * Wk[i*64 + c];
    sv += xv * Wv[i*64 + c];
  }
  qf[g] = sq; kf[g] = sk; vf[g] = sv;
}

// Verbatim r17 displaced-carry insert chain (frozen oracle — do not touch).
#define INSERT_CHAIN(DD, JJ)                                          \
  do {                                                                \
    float dd = (DD); int jj = (JJ);                                   \
    _Pragma("unroll")                                                 \
    for (int v = 0; v < 16; ++v) {                                    \
      bool sw = dd < ld[v];                                           \
      float nd = sw ? dd : ld[v]; float td = sw ? ld[v] : dd;         \
      int   nj = sw ? jj : lj[v]; int   tj = sw ? lj[v] : jj;         \
      ld[v] = nd; lj[v] = nj; dd = td; jj = tj;                       \
    }                                                                 \
  } while (0)

// Wave-0 replay with slot prefetch: pop buffered pairs in ascending-j (push)
// order with the EXACT evolving admission, then tighten + publish threshold.
// Prefetch of slot i+1 is in-bounds: cnt <= 31 < CAP0. Values consumed are
// identical to the non-prefetched form => dynamics byte-identical.
#define REPLAY0()                                                     \
  do {                                                                \
    float dnx = s_buf0[bo];                                           \
    float jnx = s_buf0[bo + 1];                                       \
    for (int i = 0; ; ++i) {                                          \
      unsigned long long alive = __ballot(i < cnt);                   \
      if (!alive) break;                                              \
      float dd0 = dnx; int jj0 = __float_as_int(jnx);                 \
      dnx = s_buf0[(i+1)*128 + bo];                                   \
      jnx = s_buf0[(i+1)*128 + bo + 1];                               \
      if (i < cnt && dd0 < ld[15]) INSERT_CHAIN(dd0, jj0);            \
    }                                                                 \
    cnt = 0; thr = ld[15]; s_thr[tid] = thr;                          \
  } while (0)

// Pipelined load/compute pieces (verbatim V1 d2 arithmetic).
#define LOADP(P, SBASE)                                               \
  _Pragma("unroll")                                                   \
  for (int u = 0; u < 8; ++u) P[u] = s_p[(SBASE) + u];

#define D2V(P)                                                        \
  float d2v[8];                                                       \
  _Pragma("unroll")                                                   \
  for (int u = 0; u < 8; ++u) {                                       \
    float acc = __fmul_rn(qx, P[u].x);                                \
    acc = __fmaf_rn(qy, P[u].y, acc);                                 \
    acc = __fmaf_rn(qz, P[u].z, acc);                                 \
    d2v[u] = __fsub_rn(__fadd_rn(sqn, P[u].w), __fmul_rn(2.0f, acc)); \
  }

// Combined (non-pipelined) group for the rare fallback path.
#define GROUP_D2(SBASE) float4 p[8]; LOADP(p, SBASE) D2V(p)

// Branchless store-offset tree: flags independent, offsets via 3-level adds.
#define TREE_OFFS(THRV)                                               \
  int f0 = (d2v[0] < (THRV)) ? 1 : 0, f1 = (d2v[1] < (THRV)) ? 1 : 0, \
      f2 = (d2v[2] < (THRV)) ? 1 : 0, f3 = (d2v[3] < (THRV)) ? 1 : 0, \
      f4 = (d2v[4] < (THRV)) ? 1 : 0, f5 = (d2v[5] < (THRV)) ? 1 : 0, \
      f6 = (d2v[6] < (THRV)) ? 1 : 0, f7 = (d2v[7] < (THRV)) ? 1 : 0; \
  int s01 = f0+f1, s23 = f2+f3, s45 = f4+f5, s67 = f6+f7;             \
  int s03 = s01+s23, s47 = s45+s67;                                   \
  int o[8];                                                           \
  o[0] = cnt;        o[1] = cnt + f0;   o[2] = cnt + s01;             \
  o[3] = cnt + s01 + f2;                o[4] = cnt + s03;             \
  o[5] = o[4] + f4;  o[6] = o[4] + s45; o[7] = o[6] + f6;

// Per-group processing bodies (each self-braced: TREE_OFFS/D2V locals scoped).
#define PROC_BOOT(P, S) {                                             \
    D2V(P)                                                            \
    _Pragma("unroll")                                                 \
    for (int u = 0; u < 8; ++u) {                                     \
      float d2 = d2v[u];                                              \
      if (d2 < ld[15]) INSERT_CHAIN(d2, (S) + u);                     \
    }                                                                 \
  }

#define PROC_W0(P, S) {                                               \
    D2V(P)                                                            \
    TREE_OFFS(thr)                                                    \
    _Pragma("unroll")                                                 \
    for (int u = 0; u < 8; ++u) {                                     \
      s_buf0[o[u]*128 + bo]     = d2v[u];                             \
      s_buf0[o[u]*128 + bo + 1] = __int_as_float((S) + u);            \
    }                                                                 \
    cnt += s03 + s47;                                                 \
    int done = (S) + 8;                                               \
    bool pub = ((done & 127) == 0) && done >= 256 && done <= 896;     \
    if (pub || __ballot(cnt >= TRIG) != 0ULL) {                       \
      REPLAY0();                                                      \
      if (pub) {                                                      \
        __threadfence_block();                                        \
        s_gen = (done >> 7) - 1;                                      \
      }                                                               \
    }                                                                 \
  }

#define PROC_W13(P, S) {                                              \
    D2V(P)                                                            \
    TREE_OFFS(thrW)                                                   \
    _Pragma("unroll")                                                 \
    for (int u = 0; u < 8; ++u) {                                     \
      int oc = (o[u] <= CAP1) ? o[u] : CAP1;                          \
      jb[oc*64 + tid] = (S) + u;                                      \
    }                                                                 \
    cnt += s03 + s47;                                                 \
  }

__global__ __launch_bounds__(256) void knn_gated4_kernel(
    const float* __restrict__ pos, int* __restrict__ idx_out) {
  __shared__ __align__(16) float4 s_p[NPTS];           // 64 KB (x,y,z,sq)
  __shared__ __align__(16) float  s_buf0[CAP0*128];    // 16 KB wave-0 (d2,j) pairs
  __shared__ int   s_j1[3][(CAP1+1)*64];               // 54.75 KB j-only buffers
  __shared__ float s_thr[64];                          // published exact ld15(P)
  __shared__ int   s_cnt1[3][64];
  __shared__ int   s_gen;                              // publish generation
  __shared__ int   s_ovf;

  int t = threadIdx.x;
  int tid = t & 63, w = t >> 6, b = blockIdx.y;
  const float* pb = pos + b*NPTS*3;
  for (int j = t; j < NPTS; j += 256) {
    float px = pb[j*3+0], py = pb[j*3+1], pz = pb[j*3+2];
    float sq = __fadd_rn(__fadd_rn(__fmul_rn(px,px), __fmul_rn(py,py)),
                         __fmul_rn(pz,pz));
    s_p[j] = make_float4(px, py, pz, sq);
  }
  if (t < 64) s_thr[t] = INFINITY;
  if (t == 0) { s_ovf = 0; s_gen = 0; }
  __syncthreads();

  int n = blockIdx.x * 64 + tid;
  float4 qp = s_p[n];
  float qx = qp.x, qy = qp.y, qz = qp.z, sqn = qp.w;
  float ld[16]; int lj[16];
#pragma unroll
  for (int u = 0; u < 16; ++u) { ld[u] = INFINITY; lj[u] = 0x7fffffff; }

  float4 pA[8], pB[8];

  // --- exact bootstrap [0, BOOT): all 4 waves run identically, pipelined ---
  LOADP(pA, 0)
  for (int s = 0; s < BOOT; s += 16) {
    LOADP(pB, s + 8)
    PROC_BOOT(pA, s)
    LOADP(pA, s + 16)        // final iter preloads group at BOOT (in-bounds)
    PROC_BOOT(pB, s + 8)
  }
  float thr = ld[15];
  int bo = tid << 1;
  int cnt = 0;

  if (w == 0) {
    // --- wave 0: exact filter+replay over [BOOT, C1S), gated publishes ---
    // pA already holds the group at BOOT from the bootstrap pipeline.
    for (int s = BOOT; s < C1S; s += 16) {
      LOADP(pB, s + 8)
      PROC_W0(pA, s)
      LOADP(pA, s + 16)      // final iter reads s_p[928..935] (in-bounds, unused)
      PROC_W0(pB, s + 8)
    }
    REPLAY0();          // state now == exact serial through j < C1S
    __syncthreads();    // waves 1-3 finished buffering

    int ovf = s_ovf;
    for (int ch = 0; ch < 3; ++ch) {
      int cs = C1S + ch*CHSZ;
      if (ovf & (1 << ch)) {
        // exact serial fallback over this chunk (correctness guarantee)
        int ce = cs + CHSZ;
        for (int s = cs; s < ce; s += 8) {
          GROUP_D2(s)
          TREE_OFFS(thr)
#pragma unroll
          for (int u = 0; u < 8; ++u) {
            s_buf0[o[u]*128 + bo]     = d2v[u];
            s_buf0[o[u]*128 + bo + 1] = __int_as_float(s + u);
          }
          cnt += s03 + s47;
          if (__ballot(cnt >= TRIG) != 0ULL) REPLAY0();
        }
        REPLAY0();
      } else {
        // merge-replay chunk buffer (ascending j, exact admission), pipelined
        const int* jb = &s_j1[ch][0];
        int cc = s_cnt1[ch][tid];
        int jn = (0 < cc) ? jb[tid] : 0;
        float4 pn = s_p[jn];
        for (int i = 0; ; ++i) {
          unsigned long long alive = __ballot(i < cc);
          if (!alive) break;
          int jj0 = jn; float4 pj = pn;
          int ix = i + 1;
          jn = (ix < cc) ? jb[ix*64 + tid] : 0;
          pn = s_p[jn];
          if (i < cc) {
            // bit-identical d2 recompute (same inputs, same fp ops as filter)
            float acc = __fmul_rn(qx, pj.x);
            acc = __fmaf_rn(qy, pj.y, acc);
            acc = __fmaf_rn(qz, pj.z, acc);
            float dd0 = __fsub_rn(__fadd_rn(sqn, pj.w), __fmul_rn(2.0f, acc));
            if (dd0 < ld[15]) INSERT_CHAIN(dd0, jj0);
          }
        }
      }
    }
    int* outp = idx_out + (b*NPTS + n)*KNN;
#pragma unroll
    for (int u = 0; u < 16; ++u) outp[u] = b*NPTS + lj[u];   // GLOBAL row index
  } else {
    // --- waves 1-3: gen-gated superset filter over their chunk, j-only ---
    int cs = C1S + (w-1)*CHSZ;
    int* jb = &s_j1[w-1][0];
    float thrW = thr;
#pragma unroll 1
    for (int seg = 0; seg < 3; ++seg) {
      int need = 2*seg + 2;                       // gens 2,4,6 -> P=384,640,896
      while (*((volatile int*)&s_gen) < need) __builtin_amdgcn_s_sleep(2);
      thrW = fminf(thrW, *((volatile float*)&s_thr[tid]));
      int ss = cs + seg*SEG, se = ss + SEG;
      LOADP(pA, ss)
      for (int s = ss; s < se; s += 16) {
        LOADP(pB, s + 8)
        PROC_W13(pA, s)
        int sn = s + 16; if (sn >= se) sn = ss;   // uniform clamp (avoids OOB)
        LOADP(pA, sn)
        PROC_W13(pB, s + 8)
      }
    }
    s_cnt1[w-1][tid] = (cnt <= CAP1) ? cnt : CAP1;
    if (cnt > CAP1) atomicOr(&s_ovf, 1 << (w-1));
    __syncthreads();
  }
}

// ---------------------------------------------------------------------------
// Fused layer r28: r27 structure (conflict-free b32 weights + readlane
// broadcast) with LDS cut to exactly 40 KB => 4 blocks/CU:
//   s_pw2 (768f) + s_h (192f) + s_j (16i) alias into s_t2's 1024f storage.
//   Lifetimes: aliased data consumed in section 1; s_t2 written after
//   matmul2. A barrier after section 1 makes the reuse race-free.
// Weight staging vectorized (float4) — values byte-identical.
// ---------------------------------------------------------------------------
__device__ __forceinline__ float wsum64(float v) {
  v += __shfl_xor(v, 1);
  v += __shfl_xor(v, 2);
  v += __shfl_xor(v, 4);
  v += __shfl_xor(v, 8);
  v += __shfl_xor(v, 16);
  v += __shfl_xor(v, 32);
  return v;
}

__device__ __forceinline__ float bcast(float v, int lane) {
  return __int_as_float(__builtin_amdgcn_readlane(__float_as_int(v), lane));
}

__global__ __launch_bounds__(256) void fuse_kernel(
    const float* __restrict__ pos, const int* __restrict__ idx,
    const float* __restrict__ qf, const float* __restrict__ kf,
    const float* __restrict__ vf,
    const float* __restrict__ p_w1, const float* __restrict__ p_b1,
    const float* __restrict__ p_g, const float* __restrict__ p_be,
    const float* __restrict__ p_w2, const float* __restrict__ p_b2,
    const float* __restrict__ a_w1, const float* __restrict__ a_b1,
    const float* __restrict__ a_g, const float* __restrict__ a_be,
    const float* __restrict__ a_w2, const float* __restrict__ a_b2,
    float* __restrict__ out) {
  __shared__ __align__(16) float s_ve[16][64];    // 4 KB
  __shared__ __align__(16) float s_t2[16][64];    // 4 KB; phase-1: pw2|h|j
  __shared__ __align__(16) float s_w1[4096];      // 16 KB  a_w1 natural [i][c]
  __shared__ __align__(16) float s_w2[4096];      // 16 KB  a_w2 natural [i][c]
  // phase-1 aliases inside s_t2 (976 of 1024 floats used)
  float* s_pw2 = &s_t2[0][0];          // 768 floats: p_w2 [h][c]
  float* s_hF  = s_pw2 + 768;          // 192 floats: s_h [k][12]
  int*   s_j   = (int*)(s_hF + 192);   // 16 ints

  int tid = threadIdx.x;
  int p = blockIdx.x;
  int c = tid & 63, kq = tid >> 6;

  // vectorized staging (coalesced float4 loads, conflict-free b128 writes)
  {
    const float4* w1v = (const float4*)a_w1;
    const float4* w2v = (const float4*)a_w2;
    float4* s1v = (float4*)s_w1;
    float4* s2v = (float4*)s_w2;
    for (int e = tid; e < 1024; e += 256) { s1v[e] = w1v[e]; s2v[e] = w2v[e]; }
    const float4* pwv = (const float4*)p_w2;
    float4* spv = (float4*)s_pw2;
    if (tid < 192) spv[tid] = pwv[tid];
  }

  if (tid < 16) {
    int j = idx[p*KNN + tid];
    s_j[tid] = j;
    float rx = pos[p*3+0] - pos[j*3+0];
    float ry = pos[p*3+1] - pos[j*3+1];
    float rz = pos[p*3+2] - pos[j*3+2];
    float hv[12];
    float mean = 0.f;
#pragma unroll
    for (int h = 0; h < 12; ++h) {
      float v = rx*p_w1[h] + ry*p_w1[12+h] + rz*p_w1[24+h] + p_b1[h];
      hv[h] = v; mean += v;
    }
    mean *= (1.0f/12.0f);
    float var = 0.f;
#pragma unroll
    for (int h = 0; h < 12; ++h) { float d = hv[h] - mean; var += d*d; }
    var *= (1.0f/12.0f);
    float rs = rsqrtf(var + LN_EPS);
#pragma unroll
    for (int h = 0; h < 12; ++h) {
      float a = (hv[h] - mean)*rs*p_g[h] + p_be[h];
      s_hF[tid*12 + h] = fmaxf(a, 0.f);
    }
  }
  __syncthreads();

  // --- section 1: pos-enc + win (REGISTERS) + ve (LDS, needed by softmax) ---
  float win0, win1, win2, win3;   // win[k][c], k = kq, 4+kq, 8+kq, 12+kq
  {
    float qv = qf[p*64 + c];
    float pb2 = p_b2[c];
    float pe0 = pb2, pe1 = pb2, pe2 = pb2, pe3 = pb2;
#pragma unroll
    for (int h = 0; h < 12; ++h) {
      float wv = s_pw2[h*64 + c];
      pe0 = __fmaf_rn(s_hF[kq*12 + h],      wv, pe0);
      pe1 = __fmaf_rn(s_hF[(4+kq)*12 + h],  wv, pe1);
      pe2 = __fmaf_rn(s_hF[(8+kq)*12 + h],  wv, pe2);
      pe3 = __fmaf_rn(s_hF[(12+kq)*12 + h], wv, pe3);
    }
    int j0 = s_j[kq], j1 = s_j[4+kq], j2 = s_j[8+kq], j3 = s_j[12+kq];
    win0 = qv - kf[j0*64 + c] + pe0;  s_ve[kq][c]    = vf[j0*64 + c] + pe0;
    win1 = qv - kf[j1*64 + c] + pe1;  s_ve[4+kq][c]  = vf[j1*64 + c] + pe1;
    win2 = qv - kf[j2*64 + c] + pe2;  s_ve[8+kq][c]  = vf[j2*64 + c] + pe2;
    win3 = qv - kf[j3*64 + c] + pe3;  s_ve[12+kq][c] = vf[j3*64 + c] + pe3;
  }
  __syncthreads();   // all waves done reading pw2/h/j before s_t2 is written

  // --- matmul1: ai = win @ a_w1 + b1 (readlane broadcast, b32 weight read) ---
  float ab1 = a_b1[c];
  float a0 = ab1, a1 = ab1, a2 = ab1, a3 = ab1;
#pragma unroll
  for (int i = 0; i < 64; ++i) {
    float wv = s_w1[i*64 + c];      // conflict-free: 64 consecutive floats
    float b0 = bcast(win0, i), b1 = bcast(win1, i);
    float b2 = bcast(win2, i), b3 = bcast(win3, i);
    a0 = __fmaf_rn(b0, wv, a0);
    a1 = __fmaf_rn(b1, wv, a1);
    a2 = __fmaf_rn(b2, wv, a2);
    a3 = __fmaf_rn(b3, wv, a3);
  }

  // --- LN + ReLU in registers (same butterfly order as r22) ---
  float ag = a_g[c], abe = a_be[c];
  float r0, r1, r2, r3;
  {
    float m = wsum64(a0) * (1.0f/64.0f); float d = a0 - m;
    float var = wsum64(d*d) * (1.0f/64.0f);
    r0 = fmaxf(d*rsqrtf(var + LN_EPS)*ag + abe, 0.f);
  }
  {
    float m = wsum64(a1) * (1.0f/64.0f); float d = a1 - m;
    float var = wsum64(d*d) * (1.0f/64.0f);
    r1 = fmaxf(d*rsqrtf(var + LN_EPS)*ag + abe, 0.f);
  }
  {
    float m = wsum64(a2) * (1.0f/64.0f); float d = a2 - m;
    float var = wsum64(d*d) * (1.0f/64.0f);
    r2 = fmaxf(d*rsqrtf(var + LN_EPS)*ag + abe, 0.f);
  }
  {
    float m = wsum64(a3) * (1.0f/64.0f); float d = a3 - m;
    float var = wsum64(d*d) * (1.0f/64.0f);
    r3 = fmaxf(d*rsqrtf(var + LN_EPS)*ag + abe, 0.f);
  }

  // --- matmul2: t2 = act @ a_w2 + b2 ---
  float ab2 = a_b2[c];
  float t0 = ab2, t1 = ab2, t2 = ab2, t3 = ab2;
#pragma unroll
  for (int i = 0; i < 64; ++i) {
    float wv = s_w2[i*64 + c];
    float b0 = bcast(r0, i), b1 = bcast(r1, i);
    float b2 = bcast(r2, i), b3 = bcast(r3, i);
    t0 = __fmaf_rn(b0, wv, t0);
    t1 = __fmaf_rn(b1, wv, t1);
    t2 = __fmaf_rn(b2, wv, t2);
    t3 = __fmaf_rn(b3, wv, t3);
  }
  s_t2[kq][c]    = t0;
  s_t2[4+kq][c]  = t1;
  s_t2[8+kq][c]  = t2;
  s_t2[12+kq][c] = t3;
  __syncthreads();

  if (tid < 64) {
    float mx = -INFINITY;
    for (int k = 0; k < 16; ++k) mx = fmaxf(mx, s_t2[k][tid]);
    float se = 0.f, po = 0.f;
    for (int k = 0; k < 16; ++k) {
      float e = expf(s_t2[k][tid] - mx);
      se += e; po += e * s_ve[k][tid];
    }
    out[p*64 + tid] = po / se;
  }
}

// ---------------------------------------------------------------------------
extern "C" void kernel_launch(void* const* d_in, const int* in_sizes, int n_in,
                              void* d_out, int out_size, void* d_ws, size_t ws_size,
                              hipStream_t stream) {
  const float* x    = (const float*)d_in[0];
  const float* pos  = (const float*)d_in[1];
  const float* Wq   = (const float*)d_in[2];
  const float* Wk   = (const float*)d_in[3];
  const float* Wv   = (const float*)d_in[4];
  const float* p_w1 = (const float*)d_in[5];
  const float* p_b1 = (const float*)d_in[6];
  const float* p_g  = (const float*)d_in[7];
  const float* p_be = (const float*)d_in[8];
  const float* p_w2 = (const float*)d_in[9];
  const float* p_b2 = (const float*)d_in[10];
  const float* a_w1 = (const float*)d_in[11];
  const float* a_b1 = (const float*)d_in[12];
  const float* a_g  = (const float*)d_in[13];
  const float* a_be = (const float*)d_in[14];
  const float* a_w2 = (const float*)d_in[15];
  const float* a_b2 = (const float*)d_in[16];

  float* ws   = (float*)d_ws;
  float* qf   = ws;                    // 1048576 floats
  float* kf   = qf + 1048576;          // 1048576
  float* vf   = kf + 1048576;          // 1048576
  int*   idx  = (int*)(vf + 1048576);  // 262144 ints
  float* outp = (float*)d_out;

  hipLaunchKernelGGL(proj3_kernel, dim3(4096), dim3(256), 0, stream,
                     x, Wq, Wk, Wv, qf, kf, vf);
  hipLaunchKernelGGL(knn_gated4_kernel, dim3(64, 4), dim3(256), 0, stream,
                     pos, idx);
  hipLaunchKernelGGL(fuse_kernel, dim3(16384), dim3(256), 0, stream,
                     pos, idx, qf, kf, vf,
                     p_w1, p_b1, p_g, p_be, p_w2, p_b2,
                     a_w1, a_b1, a_g, a_be, a_w2, a_b2, outp);
}